// Round 14
// baseline (180.533 us; speedup 1.0000x reference)
//
#include <hip/hip_runtime.h>
#include <cmath>
#include <cstdint>

// Problem constants (fixed by reference file)
#define B_     8
#define NH_    32
#define HD_    128
#define HID_   4096
#define MAXS_  4096
#define NPAIR_ (B_ * NH_)          // 256 (b,h) pairs
#define NSPLIT_ 4                  // key-splits per pair
#define PSTR_  132                 // partial stride: m, l, pad, pad, acc[128]
#define QS_    (3 * B_ * HID_)     // qkv partial stride (one K-half)
#define NEG_BIG_ (-1e30f)

typedef float f4_ __attribute__((ext_vector_type(4)));

__device__ __forceinline__ f4_ ntload4(const float* p) {
  return __builtin_nontemporal_load((const f4_*)p);
}
__device__ __forceinline__ f4_ ld4(const float* p) {
  return *(const f4_*)p;
}
__device__ __forceinline__ float dot4(f4_ a, f4_ b) {
  f4_ m = a * b;
  return m.x + m.y + m.z + m.w;
}

// Async global->LDS stage of 16 B/lane (1 KB per wave-instruction).
// LDS dest = wave-uniform byte offset + lane*16; dynamic-LDS raw offsets
// (kernel has no static __shared__). Verified correct in round 9.
__device__ __forceinline__ void stage16(const float* gsrc, unsigned ldsoff) {
  __builtin_amdgcn_global_load_lds(
      (__attribute__((address_space(1))) void*)(uintptr_t)gsrc,
      (__attribute__((address_space(3))) void*)ldsoff,
      16, 0, 0);
}

// Shared-x GEMV: 4-wave block, 32 rows (8/wave), NSL K-slices of 256.
// Round-8/13 analysis: gemv is bound by L1/TA port traffic, and at 1-wave
// blocks HALF of that traffic is per-wave-private x re-reads. Here the 8 KB
// x-slice is staged ONCE per block into double-buffered LDS (x via ds_read,
// separate pipe) -> TA bytes/slice drop 64->40 KB (w-fraction 50%->80%) and
// x's L2 traffic drops 4x. Weights register-double-buffered as in round 11.
// Barrier discipline (round-9 trap): w-prefetch + x-stage are issued BEFORE
// the ~512cy compute, so the __syncthreads vmcnt(0) drain waits on loads
// already in flight for a full phase. #pragma unroll 1 (round-10 lesson).
// Weights NORMAL loads (L3-resident across replays; nt KV can't evict).
template<int NSL>
__global__ __launch_bounds__(256) void gemv_shx(
    const float* __restrict__ W0, const float* __restrict__ W1,
    const float* __restrict__ W2, const float* __restrict__ x,
    float* __restrict__ out, int nb_per_mat, int n_inner, int part_stride)
{
  extern __shared__ float dyn[];            // [2][8][256] floats = 16 KB
  const int bid   = blockIdx.x;
  const int ks    = bid / n_inner;          // K-split index
  const int inner = bid % n_inner;
  const int m     = inner / nb_per_mat;     // matrix index (0..2)
  const int r0    = (inner % nb_per_mat) * 32;
  const float* __restrict__ W = (m == 0) ? W0 : ((m == 1) ? W1 : W2);
  float* o = out + (size_t)ks * part_stride + m * (B_ * HID_);

  const int wib  = threadIdx.x >> 6;
  const int lane = threadIdx.x & 63;
  const int kofs = ks * NSL * 256;
  const int rw   = r0 + wib * 8;            // wave's first row

  float acc[8][8];
#pragma unroll
  for (int r = 0; r < 8; ++r)
#pragma unroll
    for (int b = 0; b < 8; ++b) acc[r][b] = 0.f;

  const float* Wp = W + (size_t)rw * HID_ + kofs + lane * 4;
  const float* xp = x + kofs + lane * 4;

  f4_ wa[8], wb[8];

  // wave wib stages batches {2*wib, 2*wib+1} of x-slice u into LDS buf
#define XSTAGE_(buf, u)                                                       \
  {                                                                           \
    const int b0 = 2 * wib;                                                   \
    stage16(xp + (size_t)b0 * HID_ + (u) * 256,                               \
            (unsigned)((buf) * 8192 + b0 * 1024));                            \
    stage16(xp + (size_t)(b0 + 1) * HID_ + (u) * 256,                         \
            (unsigned)((buf) * 8192 + (b0 + 1) * 1024));                      \
  }

#define WPRE_(BUF, u)                                                         \
  {                                                                           \
    _Pragma("unroll")                                                         \
    for (int r = 0; r < 8; ++r)                                               \
      BUF[r] = ld4(Wp + (size_t)r * HID_ + (u) * 256);                        \
  }

#define COMP_(BUF, buf)                                                       \
  {                                                                           \
    f4_ xv[8];                                                                \
    _Pragma("unroll")                                                         \
    for (int b = 0; b < 8; ++b)                                               \
      xv[b] = ld4(&dyn[(buf) * 2048 + b * 256 + lane * 4]);                   \
    _Pragma("unroll")                                                         \
    for (int r = 0; r < 8; ++r)                                               \
      _Pragma("unroll")                                                       \
      for (int b = 0; b < 8; ++b) acc[r][b] += dot4(BUF[r], xv[b]);           \
  }

  // prologue: slice 0 -> (wa, LDS buf0)
  WPRE_(wa, 0);
  XSTAGE_(0, 0);
  __syncthreads();

#pragma unroll 1
  for (int u = 0; u < NSL; u += 2) {
    // phase A: prefetch slice u+1 into (wb, buf1); compute slice u
    WPRE_(wb, u + 1);
    XSTAGE_(1, u + 1);
    COMP_(wa, 0);
    __syncthreads();
    // phase B: prefetch slice u+2 into (wa, buf0); compute slice u+1
    if (u + 2 < NSL) {
      WPRE_(wa, u + 2);
      XSTAGE_(0, u + 2);
    }
    COMP_(wb, 1);
    __syncthreads();
  }
#undef XSTAGE_
#undef WPRE_
#undef COMP_

  // butterfly reduce each of the 64 partials across the wave
#pragma unroll
  for (int r = 0; r < 8; ++r)
#pragma unroll
    for (int b = 0; b < 8; ++b) {
      float v = acc[r][b];
#pragma unroll
      for (int off = 32; off; off >>= 1) v += __shfl_xor(v, off);
      acc[r][b] = v;
    }

  if (lane == 0) {
#pragma unroll
    for (int r = 0; r < 8; ++r)
#pragma unroll
      for (int b = 0; b < 8; ++b)
        o[(size_t)b * HID_ + rw + r] = acc[r][b];
  }
}

// out[i] = sum of 4 K-split partials (deterministic, no atomics).
__global__ __launch_bounds__(256) void sum4(
    const float* __restrict__ part, float* __restrict__ out)
{
  const int gid = blockIdx.x * 256 + threadIdx.x;   // 8192 f4 elements
  const int i = gid * 4;
  f4_ v = ld4(part + i) + ld4(part + (B_ * HID_) + i)
        + ld4(part + 2 * (B_ * HID_) + i) + ld4(part + 3 * (B_ * HID_) + i);
  *(f4_*)(out + i) = v;
}

// Flash-decoding partials: 4 blocks (256 thr = 4 waves) per (b,h) pair.
// q/k/v-fresh are the SUM of the two QKV K-split halves (qkv, qkv+QS_).
// K/V rows nt (stream-once; must not evict L3-resident weights).
__global__ __launch_bounds__(256, 4) void attn_partial(
    const float* __restrict__ qkv, const float* __restrict__ ck,
    const float* __restrict__ cv, const int* __restrict__ ppos,
    float* __restrict__ part)
{
  __shared__ float sm[4], sl[4];
  __shared__ float sacc[4][HD_];

  const int pos  = *ppos;
  const int bid  = blockIdx.x;
  const int pair = bid >> 2;
  const int s    = bid & (NSPLIT_ - 1);
  const int b    = pair >> 5;
  const int h    = pair & (NH_ - 1);
  const int w    = threadIdx.x >> 6;
  const int lane = threadIdx.x & 63;
  const int half = lane >> 5, l32 = lane & 31;
  const int k0   = s * 512 + w * 128;

  float m = NEG_BIG_, l = 0.f;
  f4_ acc = (f4_)0.f;

  if (k0 <= pos) {
    const float scale = 0.08838834764831845f;   // 1/sqrt(128)
    const int hoff = b * HID_ + h * HD_ + l32 * 4;
    f4_ q4  = (ld4(qkv + hoff) + ld4(qkv + QS_ + hoff)) * scale;
    f4_ kf4 =  ld4(qkv + B_ * HID_ + hoff) + ld4(qkv + QS_ + B_ * HID_ + hoff);
    f4_ vf4 =  ld4(qkv + 2 * B_ * HID_ + hoff) + ld4(qkv + QS_ + 2 * B_ * HID_ + hoff);
    const float* ckh = ck + ((size_t)(b * NH_ + h)) * MAXS_ * HD_;
    const float* cvh = cv + ((size_t)(b * NH_ + h)) * MAXS_ * HD_;

    for (int c = 0; c < 8; ++c) {
      const int kbase = k0 + c * 16;
      f4_ k4[8], v4[8];
#pragma unroll
      for (int j = 0; j < 8; ++j) {
        const int ki = kbase + 2 * j + half;
        k4[j] = ntload4(ckh + (size_t)ki * HD_ + l32 * 4);
        v4[j] = ntload4(cvh + (size_t)ki * HD_ + l32 * 4);
      }
      // fresh-token overwrite (ki==pos row of the cache is stale)
#pragma unroll
      for (int j = 0; j < 8; ++j) {
        const int ki = kbase + 2 * j + half;
        if (ki == pos) { k4[j] = kf4; v4[j] = vf4; }
      }

      float sc[8];
#pragma unroll
      for (int j = 0; j < 8; ++j) sc[j] = dot4(q4, k4[j]);

#pragma unroll
      for (int off = 16; off >= 1; off >>= 1)
#pragma unroll
        for (int j = 0; j < 8; ++j) sc[j] += __shfl_xor(sc[j], off);

#pragma unroll
      for (int j = 0; j < 8; ++j) {
        const int ki = kbase + 2 * j + half;
        if (ki > pos) sc[j] = -INFINITY;
      }

      const float cm = fmaxf(fmaxf(fmaxf(sc[0], sc[1]), fmaxf(sc[2], sc[3])),
                             fmaxf(fmaxf(sc[4], sc[5]), fmaxf(sc[6], sc[7])));
      const float mn   = fmaxf(m, cm);
      const float corr = __expf(m - mn);
      float p[8], ps = 0.f;
#pragma unroll
      for (int j = 0; j < 8; ++j) { p[j] = __expf(sc[j] - mn); ps += p[j]; }
      l = l * corr + ps;
      acc *= corr;
#pragma unroll
      for (int j = 0; j < 8; ++j) acc += p[j] * v4[j];
      m = mn;
    }
  }

  const float mo = __shfl_xor(m, 32);
  const float lo = __shfl_xor(l, 32);
  f4_ ao;
  ao.x = __shfl_xor(acc.x, 32); ao.y = __shfl_xor(acc.y, 32);
  ao.z = __shfl_xor(acc.z, 32); ao.w = __shfl_xor(acc.w, 32);
  const float mm = fmaxf(m, mo);
  const float w0 = __expf(m - mm), w1 = __expf(mo - mm);
  const float lm = l * w0 + lo * w1;
  f4_ am = acc * w0 + ao * w1;

  if (half == 0) {
    *(f4_*)&sacc[w][l32 * 4] = am;
    if (l32 == 0) { sm[w] = mm; sl[w] = lm; }
  }
  __syncthreads();

  if (threadIdx.x < 32) {
    const int t = threadIdx.x;
    float mg = NEG_BIG_;
#pragma unroll
    for (int u = 0; u < 4; ++u)
      if (sl[u] > 0.f) mg = fmaxf(mg, sm[u]);
    float ls = 0.f;
    f4_ o = (f4_)0.f;
#pragma unroll
    for (int u = 0; u < 4; ++u)
      if (sl[u] > 0.f) {
        const float wu = __expf(sm[u] - mg);
        ls += sl[u] * wu;
        o  += wu * ld4(&sacc[u][t * 4]);
      }
    float* pb = part + (size_t)bid * PSTR_;
    *(f4_*)(pb + 4 + t * 4) = o;
    if (t == 0) { pb[0] = (ls > 0.f) ? mg : NEG_BIG_; pb[1] = ls; }
  }
}

// Merge the 4 split partials per (b,h) into attn output [b][h*128+d].
__global__ __launch_bounds__(128) void attn_combine(
    const float* __restrict__ part, float* __restrict__ attnout)
{
  const int pair = blockIdx.x;
  const int d    = threadIdx.x;
  const float* pb = part + (size_t)pair * NSPLIT_ * PSTR_;

  float mg = NEG_BIG_;
#pragma unroll
  for (int u = 0; u < NSPLIT_; ++u) {
    const float lu = pb[u * PSTR_ + 1];
    if (lu > 0.f) mg = fmaxf(mg, pb[u * PSTR_]);
  }
  float ls = 0.f, o = 0.f;
#pragma unroll
  for (int u = 0; u < NSPLIT_; ++u) {
    const float lu = pb[u * PSTR_ + 1];
    if (lu > 0.f) {
      const float wu = __expf(pb[u * PSTR_] - mg);
      ls += lu * wu;
      o  += wu * pb[u * PSTR_ + 4 + d];
    }
  }
  attnout[pair * HD_ + d] = o / ls;
}

extern "C" void kernel_launch(void* const* d_in, const int* in_sizes, int n_in,
                              void* d_out, int out_size, void* d_ws, size_t ws_size,
                              hipStream_t stream) {
  const float* x  = (const float*)d_in[0];
  const float* ck = (const float*)d_in[1];
  const float* cv = (const float*)d_in[2];
  const float* wq = (const float*)d_in[3];
  const float* wk = (const float*)d_in[4];
  const float* wv = (const float*)d_in[5];
  const float* wo = (const float*)d_in[6];
  const int* pos  = (const int*)d_in[7];
  float* out = (float*)d_out;
  float* ws  = (float*)d_ws;

  float* qkvp    = ws;                                   // 2 * QS_ floats
  float* part    = qkvp + 2 * QS_;                       // 1024 * 132
  float* attnout = part + NPAIR_ * NSPLIT_ * PSTR_;      // B*HID
  float* wopart  = attnout + B_ * HID_;                  // 4 * B*HID

  // QKV: K-split x2, 32-row 4-wave blocks -> 768 blocks; LDS 16 KB each
  gemv_shx<8><<<2 * 3 * 128, 256, 16384, stream>>>(wq, wk, wv, x, qkvp,
                                                   128, 3 * 128, QS_);
  attn_partial<<<NPAIR_ * NSPLIT_, 256, 0, stream>>>(qkvp, ck, cv, pos, part);
  attn_combine<<<NPAIR_, 128, 0, stream>>>(part, attnout);
  // wo: K-split x4 -> 512 blocks; deterministic sum after
  gemv_shx<4><<<4 * 128, 256, 16384, stream>>>(wo, wo, wo, attnout, wopart,
                                               128, 128, B_ * HID_);
  sum4<<<(B_ * HID_) / (256 * 4), 256, 0, stream>>>(wopart, out);
}

// Round 15
// 176.403 us; speedup vs baseline: 1.0234x; 1.0234x over previous
//
#include <hip/hip_runtime.h>
#include <cmath>

// Problem constants (fixed by reference file)
#define B_     8
#define NH_    32
#define HD_    128
#define HID_   4096
#define MAXS_  4096
#define NPAIR_ (B_ * NH_)          // 256 (b,h) pairs
#define NEG_BIG_ (-1e30f)

typedef float f4_ __attribute__((ext_vector_type(4)));

__device__ __forceinline__ f4_ ntload4(const float* p) {
  return __builtin_nontemporal_load((const f4_*)p);
}
__device__ __forceinline__ f4_ ld4(const float* p) {
  return *(const f4_*)p;
}
__device__ __forceinline__ float dot4(f4_ a, f4_ b) {
  f4_ m = a * b;
  return m.x + m.y + m.z + m.w;
}

// Fully software-pipelined GEMV (round-13 best): 1 wave/block, 8 rows, NSL
// K-slices of 256. BOTH w and x register-prefetched one slice ahead (static
// buffer indices); 8w+8x per slice keeps weights at 50% of VMEM bytes.
// Weight stream runs ~2.6 TB/s regardless of structure (rounds 8-14) — this
// is the L3->CU path ceiling, so keep the simplest best kernel.
// Weights NORMAL loads (L3-resident across replays; nt KV can't evict).
template<int NSL>
__global__ __launch_bounds__(64) void gemv8p(
    const float* __restrict__ W0, const float* __restrict__ W1,
    const float* __restrict__ W2, const float* __restrict__ x,
    float* __restrict__ out, int nb_per_mat, int n_inner, int part_stride)
{
  const int bid   = blockIdx.x;
  const int ks    = bid / n_inner;          // K-split index
  const int inner = bid % n_inner;
  const int m     = inner / nb_per_mat;     // matrix index (0..2)
  const int r0    = (inner % nb_per_mat) * 8;
  const float* __restrict__ W = (m == 0) ? W0 : ((m == 1) ? W1 : W2);
  float* o = out + (size_t)ks * part_stride + m * (B_ * HID_);

  const int lane = threadIdx.x;             // 0..63
  const int kofs = ks * NSL * 256;

  float acc[8][8];
#pragma unroll
  for (int r = 0; r < 8; ++r)
#pragma unroll
    for (int b = 0; b < 8; ++b) acc[r][b] = 0.f;

  const float* Wp = W + (size_t)r0 * HID_ + kofs + lane * 4;
  const float* xp = x + kofs + lane * 4;

  f4_ wa[8], wb[8], xa[8], xb[8];
#pragma unroll
  for (int r = 0; r < 8; ++r) wa[r] = ld4(Wp + (size_t)r * HID_);
#pragma unroll
  for (int b = 0; b < 8; ++b) xa[b] = ld4(xp + b * HID_);

#pragma unroll 1
  for (int u = 0; u < NSL; u += 2) {
    {
      const int j1 = (u + 1) * 256;
#pragma unroll
      for (int r = 0; r < 8; ++r) wb[r] = ld4(Wp + (size_t)r * HID_ + j1);
#pragma unroll
      for (int b = 0; b < 8; ++b) xb[b] = ld4(xp + b * HID_ + j1);
#pragma unroll
      for (int r = 0; r < 8; ++r)
#pragma unroll
        for (int b = 0; b < 8; ++b) acc[r][b] += dot4(wa[r], xa[b]);
    }
    {
      if (u + 2 < NSL) {
        const int j2 = (u + 2) * 256;
#pragma unroll
        for (int r = 0; r < 8; ++r) wa[r] = ld4(Wp + (size_t)r * HID_ + j2);
#pragma unroll
        for (int b = 0; b < 8; ++b) xa[b] = ld4(xp + b * HID_ + j2);
      }
#pragma unroll
      for (int r = 0; r < 8; ++r)
#pragma unroll
        for (int b = 0; b < 8; ++b) acc[r][b] += dot4(wb[r], xb[b]);
    }
  }

#pragma unroll
  for (int r = 0; r < 8; ++r)
#pragma unroll
    for (int b = 0; b < 8; ++b) {
      float v = acc[r][b];
#pragma unroll
      for (int off = 32; off; off >>= 1) v += __shfl_xor(v, off);
      acc[r][b] = v;
    }

  if (lane == 0) {
#pragma unroll
    for (int r = 0; r < 8; ++r)
#pragma unroll
      for (int b = 0; b < 8; ++b)
        o[(size_t)b * HID_ + r0 + r] = acc[r][b];
  }
}

// out[i] = sum of 4 K-split partials (deterministic, no atomics).
__global__ __launch_bounds__(256) void sum4(
    const float* __restrict__ part, float* __restrict__ out)
{
  const int gid = blockIdx.x * 256 + threadIdx.x;   // 8192 f4 elements
  const int i = gid * 4;
  f4_ v = ld4(part + i) + ld4(part + (B_ * HID_) + i)
        + ld4(part + 2 * (B_ * HID_) + i) + ld4(part + 3 * (B_ * HID_) + i);
  *(f4_*)(out + i) = v;
}

// Fused flash-decoding attention: ONE block (512 thr = 8 waves) per (b,h)
// pair, combine in-block via LDS -> no separate combine dispatch. Wave w
// owns keys [w*256, w*256+256) (pos=2047 -> all 8 waves fully active).
// Halves own alternating keys; lane covers dims l32*4..+3. Per 16-key
// chunk: all 16 K+V loads up front, dot4, pipelined butterflies, one
// online-softmax update, 8 V FMAs. K/V rows nt (stream-once; must not
// evict L3-resident weights). Fresh rows overwritten from ws (inputs
// never mutated).
__global__ __launch_bounds__(512) void attn_pair(
    const float* __restrict__ qkv, const float* __restrict__ ck,
    const float* __restrict__ cv, const int* __restrict__ ppos,
    float* __restrict__ attnout)
{
  __shared__ float sm[8], sl[8];
  __shared__ float sacc[8][HD_];

  const int pos  = *ppos;
  const int pair = blockIdx.x;
  const int b    = pair >> 5;
  const int h    = pair & (NH_ - 1);
  const int w    = threadIdx.x >> 6;
  const int lane = threadIdx.x & 63;
  const int half = lane >> 5, l32 = lane & 31;
  const int k0   = w * 256;

  float m = NEG_BIG_, l = 0.f;
  f4_ acc = (f4_)0.f;

  if (k0 <= pos) {
    const float scale = 0.08838834764831845f;   // 1/sqrt(128)
    const int hoff = b * HID_ + h * HD_ + l32 * 4;
    f4_ q4  = ld4(qkv + hoff) * scale;
    f4_ kf4 = ld4(qkv + B_ * HID_ + hoff);
    f4_ vf4 = ld4(qkv + 2 * B_ * HID_ + hoff);
    const float* ckh = ck + ((size_t)(b * NH_ + h)) * MAXS_ * HD_;
    const float* cvh = cv + ((size_t)(b * NH_ + h)) * MAXS_ * HD_;

    for (int c = 0; c < 16; ++c) {
      const int kbase = k0 + c * 16;
      f4_ k4[8], v4[8];
#pragma unroll
      for (int j = 0; j < 8; ++j) {
        const int ki = kbase + 2 * j + half;
        k4[j] = ntload4(ckh + (size_t)ki * HD_ + l32 * 4);
        v4[j] = ntload4(cvh + (size_t)ki * HD_ + l32 * 4);
      }
      // fresh-token overwrite (ki==pos row of the cache is stale)
#pragma unroll
      for (int j = 0; j < 8; ++j) {
        const int ki = kbase + 2 * j + half;
        if (ki == pos) { k4[j] = kf4; v4[j] = vf4; }
      }

      float sc[8];
#pragma unroll
      for (int j = 0; j < 8; ++j) sc[j] = dot4(q4, k4[j]);

#pragma unroll
      for (int off = 16; off >= 1; off >>= 1)
#pragma unroll
        for (int j = 0; j < 8; ++j) sc[j] += __shfl_xor(sc[j], off);

#pragma unroll
      for (int j = 0; j < 8; ++j) {
        const int ki = kbase + 2 * j + half;
        if (ki > pos) sc[j] = -INFINITY;
      }

      const float cm = fmaxf(fmaxf(fmaxf(sc[0], sc[1]), fmaxf(sc[2], sc[3])),
                             fmaxf(fmaxf(sc[4], sc[5]), fmaxf(sc[6], sc[7])));
      const float mn   = fmaxf(m, cm);
      const float corr = __expf(m - mn);
      float p[8], ps = 0.f;
#pragma unroll
      for (int j = 0; j < 8; ++j) { p[j] = __expf(sc[j] - mn); ps += p[j]; }
      l = l * corr + ps;
      acc *= corr;
#pragma unroll
      for (int j = 0; j < 8; ++j) acc += p[j] * v4[j];
      m = mn;
    }
  }

  // merge the two halves of each wave
  const float mo = __shfl_xor(m, 32);
  const float lo = __shfl_xor(l, 32);
  f4_ ao;
  ao.x = __shfl_xor(acc.x, 32); ao.y = __shfl_xor(acc.y, 32);
  ao.z = __shfl_xor(acc.z, 32); ao.w = __shfl_xor(acc.w, 32);
  const float mm = fmaxf(m, mo);
  const float w0 = __expf(m - mm), w1 = __expf(mo - mm);
  const float lm = l * w0 + lo * w1;
  f4_ am = acc * w0 + ao * w1;

  if (half == 0) {
    *(f4_*)&sacc[w][l32 * 4] = am;
    if (l32 == 0) { sm[w] = mm; sl[w] = lm; }
  }
  __syncthreads();

  // final merge of the 8 wave-partials (32 threads, one f4 per thread)
  if (threadIdx.x < 32) {
    const int t = threadIdx.x;
    float mg = NEG_BIG_;
#pragma unroll
    for (int u = 0; u < 8; ++u)
      if (sl[u] > 0.f) mg = fmaxf(mg, sm[u]);
    float ls = 0.f;
    f4_ o = (f4_)0.f;
#pragma unroll
    for (int u = 0; u < 8; ++u)
      if (sl[u] > 0.f) {
        const float wu = __expf(sm[u] - mg);
        ls += sl[u] * wu;
        o  += wu * ld4(&sacc[u][t * 4]);
      }
    *(f4_*)(attnout + pair * HD_ + t * 4) = o / ls;
  }
}

extern "C" void kernel_launch(void* const* d_in, const int* in_sizes, int n_in,
                              void* d_out, int out_size, void* d_ws, size_t ws_size,
                              hipStream_t stream) {
  const float* x  = (const float*)d_in[0];
  const float* ck = (const float*)d_in[1];
  const float* cv = (const float*)d_in[2];
  const float* wq = (const float*)d_in[3];
  const float* wk = (const float*)d_in[4];
  const float* wv = (const float*)d_in[5];
  const float* wo = (const float*)d_in[6];
  const int* pos  = (const int*)d_in[7];
  float* out = (float*)d_out;
  float* ws  = (float*)d_ws;

  float* qkv     = ws;                                   // 3*8*4096 floats
  float* attnout = qkv + 3 * B_ * HID_;                  // B*HID
  float* wopart  = attnout + B_ * HID_;                  // 4 * B*HID

  // QKV: no K-split (1536 one-wave blocks; round-12 split was neutral)
  gemv8p<16><<<3 * 512, 64, 0, stream>>>(wq, wk, wv, x, qkv,
                                         512, 3 * 512, 0);
  // attention + combine fused: 256 blocks, 8 waves each
  attn_pair<<<NPAIR_, 512, 0, stream>>>(qkv, ck, cv, pos, attnout);
  // wo: K-split x4 (2048 blocks -> 8/CU), deterministic sum after
  gemv8p<4><<<4 * 512, 64, 0, stream>>>(wo, wo, wo, attnout, wopart,
                                        512, 512, B_ * HID_);
  sum4<<<(B_ * HID_) / (256 * 4), 256, 0, stream>>>(wopart, out);
}

// Round 16
// 167.354 us; speedup vs baseline: 1.0788x; 1.0541x over previous
//
#include <hip/hip_runtime.h>
#include <cmath>
#include <cstdint>

// Problem constants (fixed by reference file)
#define B_     8
#define NH_    32
#define HD_    128
#define HID_   4096
#define MAXS_  4096
#define NPAIR_ (B_ * NH_)          // 256 (b,h) pairs
#define QS_    (3 * B_ * HID_)     // qkv partial stride (one K-half)
#define NEG_BIG_ (-1e30f)

typedef float f4_ __attribute__((ext_vector_type(4)));

__device__ __forceinline__ f4_ ntload4(const float* p) {
  return __builtin_nontemporal_load((const f4_*)p);
}
__device__ __forceinline__ f4_ ld4(const float* p) {
  return *(const f4_*)p;
}
__device__ __forceinline__ float dot4(f4_ a, f4_ b) {
  f4_ m = a * b;
  return m.x + m.y + m.z + m.w;
}

// Async global->LDS stage of 16 B/lane (1 KB per wave-instruction).
// Per-lane global src; LDS dest = wave-uniform byte offset + lane*16.
// Dynamic-LDS raw offsets (no static __shared__). Verified in round 9.
__device__ __forceinline__ void stage16(const float* gsrc, unsigned ldsoff) {
  __builtin_amdgcn_global_load_lds(
      (__attribute__((address_space(1))) void*)(uintptr_t)gsrc,
      (__attribute__((address_space(3))) void*)ldsoff,
      16, 0, 0);
}

// PURE-WEIGHT-STREAM GEMV (the isolation experiment): 4-wave block, 32 rows
// (8/wave), NSL K-slices of 256. The block's ENTIRE x K-range (8 batches x
// NSL KB) is staged into LDS up front with ONE barrier; the stream loop then
// contains ONLY the register-double-buffered weight loads + ds_read_b128 x
// reads + FMAs — no VMEM x, no barriers, nothing to throttle the in-order
// vmcnt weight drain. If this still runs ~2.6 TB/s, the weight path itself
// is the wall (it held across 5 kernel structures, rounds 8-15).
// Weights NORMAL loads (L3-resident across replays; nt KV can't evict).
template<int NSL>
__global__ __launch_bounds__(256) void gemv_xlds(
    const float* __restrict__ W0, const float* __restrict__ W1,
    const float* __restrict__ W2, const float* __restrict__ x,
    float* __restrict__ out, int nb_per_mat, int n_inner, int part_stride)
{
  extern __shared__ float dyn[];            // [8][NSL][256] floats
  const int bid   = blockIdx.x;
  const int ks    = bid / n_inner;          // K-split index
  const int inner = bid % n_inner;
  const int m     = inner / nb_per_mat;     // matrix index (0..2)
  const int r0    = (inner % nb_per_mat) * 32;
  const float* __restrict__ W = (m == 0) ? W0 : ((m == 1) ? W1 : W2);
  float* o = out + (size_t)ks * part_stride + m * (B_ * HID_);

  const int wib  = threadIdx.x >> 6;
  const int lane = threadIdx.x & 63;
  const int kofs = ks * NSL * 256;
  const int rw   = r0 + wib * 8;            // wave's first row

  float acc[8][8];
#pragma unroll
  for (int r = 0; r < 8; ++r)
#pragma unroll
    for (int b = 0; b < 8; ++b) acc[r][b] = 0.f;

  const float* Wp = W + (size_t)rw * HID_ + kofs + lane * 4;
  const float* xp = x + kofs + lane * 4;

  // stage the whole x K-range: wave wib stages batches {2wib, 2wib+1}
#pragma unroll
  for (int bb = 0; bb < 2; ++bb) {
    const int b = 2 * wib + bb;
#pragma unroll
    for (int s = 0; s < NSL; ++s)
      stage16(xp + (size_t)b * HID_ + s * 256,
              (unsigned)((b * NSL + s) * 1024));
  }

  f4_ wa[8], wb[8];
#pragma unroll
  for (int r = 0; r < 8; ++r) wa[r] = ld4(Wp + (size_t)r * HID_);
  __syncthreads();                          // one-time drain; staging done

#define COMP_(BUF, u)                                                         \
  {                                                                           \
    f4_ xv[8];                                                                \
    _Pragma("unroll")                                                         \
    for (int b = 0; b < 8; ++b)                                               \
      xv[b] = ld4(&dyn[(b * NSL + (u)) * 256 + lane * 4]);                    \
    _Pragma("unroll")                                                         \
    for (int r = 0; r < 8; ++r)                                               \
      _Pragma("unroll")                                                       \
      for (int b = 0; b < 8; ++b) acc[r][b] += dot4(BUF[r], xv[b]);           \
  }

#pragma unroll 1
  for (int u = 0; u < NSL; u += 2) {
    {
#pragma unroll
      for (int r = 0; r < 8; ++r)
        wb[r] = ld4(Wp + (size_t)r * HID_ + (u + 1) * 256);
      COMP_(wa, u);
    }
    {
      if (u + 2 < NSL) {
#pragma unroll
        for (int r = 0; r < 8; ++r)
          wa[r] = ld4(Wp + (size_t)r * HID_ + (u + 2) * 256);
      }
      COMP_(wb, u + 1);
    }
  }
#undef COMP_

  // butterfly reduce each of the 64 partials across the wave
#pragma unroll
  for (int r = 0; r < 8; ++r)
#pragma unroll
    for (int b = 0; b < 8; ++b) {
      float v = acc[r][b];
#pragma unroll
      for (int off = 32; off; off >>= 1) v += __shfl_xor(v, off);
      acc[r][b] = v;
    }

  if (lane == 0) {
#pragma unroll
    for (int r = 0; r < 8; ++r)
#pragma unroll
      for (int b = 0; b < 8; ++b)
        o[(size_t)b * HID_ + rw + r] = acc[r][b];
  }
}

// out[i] = sum of 4 K-split partials (deterministic, no atomics).
__global__ __launch_bounds__(256) void sum4(
    const float* __restrict__ part, float* __restrict__ out)
{
  const int gid = blockIdx.x * 256 + threadIdx.x;   // 8192 f4 elements
  const int i = gid * 4;
  f4_ v = ld4(part + i) + ld4(part + (B_ * HID_) + i)
        + ld4(part + 2 * (B_ * HID_) + i) + ld4(part + 3 * (B_ * HID_) + i);
  *(f4_*)(out + i) = v;
}

// Fused flash-decoding attention: ONE block (512 thr = 8 waves) per (b,h),
// combine in-block. q/k/v-fresh are the SUM of the two QKV K-split halves.
// K/V rows nt (stream-once; must not evict L3-resident weights).
__global__ __launch_bounds__(512) void attn_pair(
    const float* __restrict__ qkv, const float* __restrict__ ck,
    const float* __restrict__ cv, const int* __restrict__ ppos,
    float* __restrict__ attnout)
{
  __shared__ float sm[8], sl[8];
  __shared__ float sacc[8][HD_];

  const int pos  = *ppos;
  const int pair = blockIdx.x;
  const int b    = pair >> 5;
  const int h    = pair & (NH_ - 1);
  const int w    = threadIdx.x >> 6;
  const int lane = threadIdx.x & 63;
  const int half = lane >> 5, l32 = lane & 31;
  const int k0   = w * 256;

  float m = NEG_BIG_, l = 0.f;
  f4_ acc = (f4_)0.f;

  if (k0 <= pos) {
    const float scale = 0.08838834764831845f;   // 1/sqrt(128)
    const int hoff = b * HID_ + h * HD_ + l32 * 4;
    f4_ q4  = (ld4(qkv + hoff) + ld4(qkv + QS_ + hoff)) * scale;
    f4_ kf4 =  ld4(qkv + B_ * HID_ + hoff) + ld4(qkv + QS_ + B_ * HID_ + hoff);
    f4_ vf4 =  ld4(qkv + 2 * B_ * HID_ + hoff) + ld4(qkv + QS_ + 2 * B_ * HID_ + hoff);
    const float* ckh = ck + ((size_t)(b * NH_ + h)) * MAXS_ * HD_;
    const float* cvh = cv + ((size_t)(b * NH_ + h)) * MAXS_ * HD_;

    for (int c = 0; c < 16; ++c) {
      const int kbase = k0 + c * 16;
      f4_ k4[8], v4[8];
#pragma unroll
      for (int j = 0; j < 8; ++j) {
        const int ki = kbase + 2 * j + half;
        k4[j] = ntload4(ckh + (size_t)ki * HD_ + l32 * 4);
        v4[j] = ntload4(cvh + (size_t)ki * HD_ + l32 * 4);
      }
      // fresh-token overwrite (ki==pos row of the cache is stale)
#pragma unroll
      for (int j = 0; j < 8; ++j) {
        const int ki = kbase + 2 * j + half;
        if (ki == pos) { k4[j] = kf4; v4[j] = vf4; }
      }

      float sc[8];
#pragma unroll
      for (int j = 0; j < 8; ++j) sc[j] = dot4(q4, k4[j]);

#pragma unroll
      for (int off = 16; off >= 1; off >>= 1)
#pragma unroll
        for (int j = 0; j < 8; ++j) sc[j] += __shfl_xor(sc[j], off);

#pragma unroll
      for (int j = 0; j < 8; ++j) {
        const int ki = kbase + 2 * j + half;
        if (ki > pos) sc[j] = -INFINITY;
      }

      const float cm = fmaxf(fmaxf(fmaxf(sc[0], sc[1]), fmaxf(sc[2], sc[3])),
                             fmaxf(fmaxf(sc[4], sc[5]), fmaxf(sc[6], sc[7])));
      const float mn   = fmaxf(m, cm);
      const float corr = __expf(m - mn);
      float p[8], ps = 0.f;
#pragma unroll
      for (int j = 0; j < 8; ++j) { p[j] = __expf(sc[j] - mn); ps += p[j]; }
      l = l * corr + ps;
      acc *= corr;
#pragma unroll
      for (int j = 0; j < 8; ++j) acc += p[j] * v4[j];
      m = mn;
    }
  }

  // merge the two halves of each wave
  const float mo = __shfl_xor(m, 32);
  const float lo = __shfl_xor(l, 32);
  f4_ ao;
  ao.x = __shfl_xor(acc.x, 32); ao.y = __shfl_xor(acc.y, 32);
  ao.z = __shfl_xor(acc.z, 32); ao.w = __shfl_xor(acc.w, 32);
  const float mm = fmaxf(m, mo);
  const float w0 = __expf(m - mm), w1 = __expf(mo - mm);
  const float lm = l * w0 + lo * w1;
  f4_ am = acc * w0 + ao * w1;

  if (half == 0) {
    *(f4_*)&sacc[w][l32 * 4] = am;
    if (l32 == 0) { sm[w] = mm; sl[w] = lm; }
  }
  __syncthreads();

  // final merge of the 8 wave-partials (32 threads, one f4 per thread)
  if (threadIdx.x < 32) {
    const int t = threadIdx.x;
    float mg = NEG_BIG_;
#pragma unroll
    for (int u = 0; u < 8; ++u)
      if (sl[u] > 0.f) mg = fmaxf(mg, sm[u]);
    float ls = 0.f;
    f4_ o = (f4_)0.f;
#pragma unroll
    for (int u = 0; u < 8; ++u)
      if (sl[u] > 0.f) {
        const float wu = __expf(sm[u] - mg);
        ls += sl[u] * wu;
        o  += wu * ld4(&sacc[u][t * 4]);
      }
    *(f4_*)(attnout + pair * HD_ + t * 4) = o / ls;
  }
}

extern "C" void kernel_launch(void* const* d_in, const int* in_sizes, int n_in,
                              void* d_out, int out_size, void* d_ws, size_t ws_size,
                              hipStream_t stream) {
  const float* x  = (const float*)d_in[0];
  const float* ck = (const float*)d_in[1];
  const float* cv = (const float*)d_in[2];
  const float* wq = (const float*)d_in[3];
  const float* wk = (const float*)d_in[4];
  const float* wv = (const float*)d_in[5];
  const float* wo = (const float*)d_in[6];
  const int* pos  = (const int*)d_in[7];
  float* out = (float*)d_out;
  float* ws  = (float*)d_ws;

  float* qkvp    = ws;                                   // 2 * QS_ floats
  float* attnout = qkvp + 2 * QS_;                       // B*HID
  float* wopart  = attnout + B_ * HID_;                  // 4 * B*HID

  // QKV: K-split x2, 32-row 4-wave blocks, whole-x-in-LDS (64 KB each)
  gemv_xlds<8><<<2 * 3 * 128, 256, 65536, stream>>>(wq, wk, wv, x, qkvp,
                                                    128, 3 * 128, QS_);
  // attention + combine fused (sums the two qkv K-halves on load)
  attn_pair<<<NPAIR_, 512, 0, stream>>>(qkvp, ck, cv, pos, attnout);
  // wo: K-split x4, whole-x-in-LDS (32 KB each), deterministic sum after
  gemv_xlds<4><<<4 * 128, 256, 32768, stream>>>(wo, wo, wo, attnout, wopart,
                                                128, 128, B_ * HID_);
  sum4<<<(B_ * HID_) / (256 * 4), 256, 0, stream>>>(wopart, out);
}